// Round 5
// baseline (138.713 us; speedup 1.0000x reference)
//
#include <hip/hip_runtime.h>
#include <hip/hip_bf16.h>

// Problem constants (B=1)
constexpr int T_LEN  = 262144;
constexpr int H      = 64;
constexpr int S_LEN  = 8;                  // R13-validated
constexpr int WARM   = 16;                 // warm-up steps (contraction ~0.56/step -> 0.56^16 ~ 9e-5 << bf16-h floor)
constexpr int CHUNKS = T_LEN / S_LEN;      // 32768
constexpr int NWAVE  = CHUNKS / 16;        // 2048 waves
constexpr int ROWS   = WARM + 128;         // 144 z rows per wave (16 warm + 128 main)
constexpr int ZROW_DW = 33;                // dwords/z-row: 32 feat-dwords + 1 mask; ODD -> LDS bank spread

typedef __attribute__((ext_vector_type(8))) short short8;  // 8 bf16 (4 VGPRs) MFMA A/B frag
typedef __attribute__((ext_vector_type(4))) float f32x4;   // MFMA C/D frag

// Saturation-safe fast tanh: 1 - 2/(exp(2x)+1). exp overflow -> rcp(inf)=0 -> 1. No NaN.
__device__ __forceinline__ float fast_tanh(float x) {
    float e = __expf(2.0f * x);
    return 1.0f - 2.0f * __builtin_amdgcn_rcpf(e + 1.0f);
}
// bf16 round-to-nearest-even pack / unpack (scalar fallback)
__device__ __forceinline__ unsigned short f2bf(float v) {
    unsigned u = __builtin_bit_cast(unsigned, v);
    return (unsigned short)((u + 0x7fffu + ((u >> 16) & 1u)) >> 16);
}
__device__ __forceinline__ float bf2f(unsigned short b) {
    return __builtin_bit_cast(float, (unsigned)b << 16);
}
// RNE pack of two floats -> packed bf16x2 (1-instruction v_cvt_pk_bf16_f32 when available)
__device__ __forceinline__ unsigned pack2(float a, float b) {
#if __has_builtin(__builtin_amdgcn_cvt_pk_bf16_f32)
    typedef __attribute__((ext_vector_type(2))) __bf16 bf16x2;
    bf16x2 r = __builtin_amdgcn_cvt_pk_bf16_f32(a, b);
    return __builtin_bit_cast(unsigned, r);
#else
    return (unsigned)f2bf(a) | ((unsigned)f2bf(b) << 16);
#endif
}

// ---------------------------------------------------------------------------
// R15: FUSED encoder + RNN scan. Each wave is fully self-sufficient:
//   phase 1: pi-chained transposed encoder (R14 math verbatim, weights in
//            per-lane REGISTERS) over its 144 rows (16 warm recomputed from
//            the neighbor's range; t<0 rows use clamped x, consumed only
//            pre-reset), z written to a wave-private LDS slice [144][33 dw]
//            (32 feat-dwords + mask float; odd stride spreads banks).
//   phase 2: R13 scan verbatim, z/m read from LDS (~60cyc) instead of
//            L2/L3/HBM (~200-900cyc/step) — kills the step-proportional
//            latency term R12's A/B exposed. No __syncthreads anywhere.
// Deletes: 2nd launch, z/m HBM round-trip (67MB), ALL d_ws use (no
// dependency on the 256MiB re-poison fill). Bit-exact vs R14 (same f32/bf16
// op chain); absmax tripwire = 0.001464844.
// ---------------------------------------------------------------------------
__global__ __launch_bounds__(256) void fused_kernel(
    const float* __restrict__ x,
    const float* __restrict__ W1, const float* __restrict__ b1,
    const float* __restrict__ W2, const float* __restrict__ b2,
    const float* __restrict__ Wx, const float* __restrict__ b_rnn,
    const float* __restrict__ Wh, const float* __restrict__ Wm,
    const float* __restrict__ bm, float* __restrict__ out)
{
    __shared__ unsigned zsh[4][ROWS * ZROW_DW];   // 76,032 B -> 2 blocks/CU

    const int tid = threadIdx.x;
    const int w   = tid >> 6;
    const int l   = tid & 63;
    const int q   = l >> 4;
    const int n15 = l & 15;
    const int rw  = blockIdx.x * 4 + w;   // global wave id 0..2047

    unsigned* zdw = zsh[w];               // wave-private z slice

    // ---- per-lane pi-permuted encoder weight A-frags (registers) ----
    short8 w1r[4], w2r[8], w3r[8];
    #pragma unroll
    for (int mt = 0; mt < 4; ++mt) {
        const int prow = 32 * (mt >> 1) + 8 * (n15 >> 2) + 4 * (mt & 1) + (n15 & 3);
        uint4 o1 = make_uint4(0, 0, 0, 0);
        if (q < 2) {   // Dekker: k=0..7 (hi) and k=8..15 (lo) share W1 rows
            float v[8];
            #pragma unroll
            for (int j = 0; j < 8; ++j) v[j] = W1[j * 64 + prow];
            o1.x = pack2(v[0], v[1]); o1.y = pack2(v[2], v[3]);
            o1.z = pack2(v[4], v[5]); o1.w = pack2(v[6], v[7]);
        }
        w1r[mt] = __builtin_bit_cast(short8, o1);
        #pragma unroll
        for (int kh = 0; kh < 2; ++kh) {
            float v2[8], v3[8];
            #pragma unroll
            for (int j = 0; j < 8; ++j) {
                const int k = kh * 32 + q * 8 + j;
                v2[j] = W2[k * 64 + prow];
                v3[j] = Wx[k * 64 + prow];
            }
            uint4 o2, o3;
            o2.x = pack2(v2[0], v2[1]); o2.y = pack2(v2[2], v2[3]);
            o2.z = pack2(v2[4], v2[5]); o2.w = pack2(v2[6], v2[7]);
            o3.x = pack2(v3[0], v3[1]); o3.y = pack2(v3[2], v3[3]);
            o3.z = pack2(v3[4], v3[5]); o3.w = pack2(v3[6], v3[7]);
            w2r[mt * 2 + kh] = __builtin_bit_cast(short8, o2);
            w3r[mt * 2 + kh] = __builtin_bit_cast(short8, o3);
        }
    }
    // biases per lane: feature base = 32*(mt>>1) + 4*(mt&1) + 8q (16B-aligned)
    f32x4 b1v[4], b2v[4], brv[4];
    #pragma unroll
    for (int mt = 0; mt < 4; ++mt) {
        const int base = 32 * (mt >> 1) + 4 * (mt & 1) + 8 * q;
        b1v[mt] = *(const f32x4*)(b1 + base);
        b2v[mt] = *(const f32x4*)(b2 + base);
        brv[mt] = *(const f32x4*)(b_rnn + base);
    }

    // ---- phase 1: encoder, 9 groups of 16 rows, depth-1 x prefetch ----
    const int t0_abs = rw * 128 - WARM;   // abs t of block-local row 0 (may be -16 for rw==0)
    auto xoff = [&](int g) {
        int t = t0_abs + g * 16 + n15;
        if (t < 0) t = 0;                 // clamp: only rw==0 rows t<0; consumed pre-reset only
        return (size_t)t * 8;
    };
    float4 xa = *(const float4*)(x + xoff(0));
    float4 xb = *(const float4*)(x + xoff(0) + 4);

    for (int g = 0; g < 9; ++g) {
        const int T = g * 16 + n15;       // block-local z row

        float4 na = xa, nb = xb;
        if (g < 8) {
            na = *(const float4*)(x + xoff(g + 1));
            nb = *(const float4*)(x + xoff(g + 1) + 4);
        }

        // x^T B-frag, Dekker-split; q==0 also stores the mask float
        short8 xB = (short8)0;
        {
            const float xv[8] = {xa.x, xa.y, xa.z, xa.w, xb.x, xb.y, xb.z, xb.w};
            if (q == 0) {
                bool nz = false;
                #pragma unroll
                for (int d = 0; d < 8; ++d) nz = nz || (xv[d] != 0.0f);
                zdw[T * ZROW_DW + 32] = __builtin_bit_cast(unsigned, nz ? 1.0f : 0.0f);
                uint4 o;
                o.x = pack2(xv[0], xv[1]); o.y = pack2(xv[2], xv[3]);
                o.z = pack2(xv[4], xv[5]); o.w = pack2(xv[6], xv[7]);
                xB = __builtin_bit_cast(short8, o);
            } else if (q == 1) {
                float lo[8];
                #pragma unroll
                for (int d = 0; d < 8; ++d) lo[d] = xv[d] - bf2f(f2bf(xv[d]));
                uint4 o;
                o.x = pack2(lo[0], lo[1]); o.y = pack2(lo[2], lo[3]);
                o.z = pack2(lo[4], lo[5]); o.w = pack2(lo[6], lo[7]);
                xB = __builtin_bit_cast(short8, o);
            }
        }

        // L1
        f32x4 acc[4];
        #pragma unroll
        for (int mt = 0; mt < 4; ++mt)
            acc[mt] = __builtin_amdgcn_mfma_f32_16x16x32_bf16(
                w1r[mt], xB, (f32x4){0.f, 0.f, 0.f, 0.f}, 0, 0, 0);

        short8 hb0, hb1;
        {
            unsigned hw[8];
            #pragma unroll
            for (int mt = 0; mt < 4; ++mt) {
                float th[4];
                #pragma unroll
                for (int r = 0; r < 4; ++r)
                    th[r] = fast_tanh(acc[mt][r] + b1v[mt][r]);
                hw[mt * 2 + 0] = pack2(th[0], th[1]);
                hw[mt * 2 + 1] = pack2(th[2], th[3]);
            }
            hb0 = __builtin_bit_cast(short8, make_uint4(hw[0], hw[1], hw[2], hw[3]));
            hb1 = __builtin_bit_cast(short8, make_uint4(hw[4], hw[5], hw[6], hw[7]));
        }

        // L2
        #pragma unroll
        for (int mt = 0; mt < 4; ++mt) {
            f32x4 d = {0.f, 0.f, 0.f, 0.f};
            d = __builtin_amdgcn_mfma_f32_16x16x32_bf16(w2r[mt * 2 + 0], hb0, d, 0, 0, 0);
            d = __builtin_amdgcn_mfma_f32_16x16x32_bf16(w2r[mt * 2 + 1], hb1, d, 0, 0, 0);
            acc[mt] = d;
        }
        {
            unsigned hw[8];
            #pragma unroll
            for (int mt = 0; mt < 4; ++mt) {
                float th[4];
                #pragma unroll
                for (int r = 0; r < 4; ++r)
                    th[r] = fast_tanh(acc[mt][r] + b2v[mt][r]);
                hw[mt * 2 + 0] = pack2(th[0], th[1]);
                hw[mt * 2 + 1] = pack2(th[2], th[3]);
            }
            hb0 = __builtin_bit_cast(short8, make_uint4(hw[0], hw[1], hw[2], hw[3]));
            hb1 = __builtin_bit_cast(short8, make_uint4(hw[4], hw[5], hw[6], hw[7]));
        }

        // L3 + b_rnn -> z dwords, store to LDS (feats [8q,8q+8) and [32+8q,+8))
        #pragma unroll
        for (int mt = 0; mt < 4; ++mt) {
            f32x4 d = {0.f, 0.f, 0.f, 0.f};
            d = __builtin_amdgcn_mfma_f32_16x16x32_bf16(w3r[mt * 2 + 0], hb0, d, 0, 0, 0);
            d = __builtin_amdgcn_mfma_f32_16x16x32_bf16(w3r[mt * 2 + 1], hb1, d, 0, 0, 0);
            acc[mt] = d;
        }
        {
            unsigned zw[8];
            #pragma unroll
            for (int mt = 0; mt < 4; ++mt) {
                zw[mt * 2 + 0] = pack2(acc[mt][0] + brv[mt][0], acc[mt][1] + brv[mt][1]);
                zw[mt * 2 + 1] = pack2(acc[mt][2] + brv[mt][2], acc[mt][3] + brv[mt][3]);
            }
            #pragma unroll
            for (int i = 0; i < 4; ++i) {
                zdw[T * ZROW_DW + 4 * q + i]      = zw[i];
                zdw[T * ZROW_DW + 16 + 4 * q + i] = zw[4 + i];
            }
        }

        xa = na; xb = nb;
    }
    __builtin_amdgcn_wave_barrier();   // phase fence; lgkmcnt hazards compiler-tracked

    // ---- scan weights (registers; loaded after encoder to cap peak VGPR) ----
    short8 afrag[8];
    #pragma unroll
    for (int tn = 0; tn < 4; ++tn) {
        const int prow = 32 * (tn >> 1) + 8 * (n15 >> 2) + 4 * (tn & 1) + (n15 & 3);
        #pragma unroll
        for (int kh = 0; kh < 2; ++kh) {
            short8 s;
            #pragma unroll
            for (int j = 0; j < 8; ++j)
                s[j] = (short)f2bf(Wh[(kh * 32 + q * 8 + j) * 64 + prow]);
            afrag[tn * 2 + kh] = s;
        }
    }
    short8 wmf[2];
    #pragma unroll
    for (int kh = 0; kh < 2; ++kh) {
        short8 s;
        #pragma unroll
        for (int j = 0; j < 8; ++j)
            s[j] = (n15 < 4) ? (short)f2bf(Wm[(kh * 32 + q * 8 + j) * 4 + n15]) : (short)0;
        wmf[kh] = s;
    }
    const float4 bmv = *(const float4*)bm;

    // ---- phase 2: scan (R13 verbatim, z/m from LDS) ----
    short8 hB[2];
    hB[0] = (short8)0;
    hB[1] = (short8)0;
    const int c    = rw * 16 + n15;       // this lane's chunk
    const int tneg = -(c * S_LEN);        // st at which abs t == 0 (rw==0, n15<=2 reachable)

    auto body = [&](int st, bool means_prev, bool may_reset) {
        // z + mask reads for THIS step, issued first (hidden under the MFMAs)
        const unsigned* zd = zdw + (unsigned)(8 * n15 + st + WARM) * ZROW_DW;
        unsigned zc[8];
        #pragma unroll
        for (int i = 0; i < 4; ++i) {
            zc[i]     = zd[4 * q + i];
            zc[4 + i] = zd[16 + 4 * q + i];
        }
        const float mf = __builtin_bit_cast(float, zd[32]);

        if (may_reset && rw == 0) {       // uniform branch: 2047/2048 waves skip
            if (st == tneg) { hB[0] = (short8)0; hB[1] = (short8)0; }
        }
        // preact^T(pi) = pi-rows(Wh^T) @ h^T
        f32x4 acc[4];
        #pragma unroll
        for (int mt = 0; mt < 4; ++mt) {
            f32x4 d = {0.f, 0.f, 0.f, 0.f};
            d = __builtin_amdgcn_mfma_f32_16x16x32_bf16(afrag[mt * 2 + 0], hB[0], d, 0, 0, 0);
            d = __builtin_amdgcn_mfma_f32_16x16x32_bf16(afrag[mt * 2 + 1], hB[1], d, 0, 0, 0);
            acc[mt] = d;
        }
        // means of the PREVIOUS step's h
        if (means_prev) {
            f32x4 a2 = {0.f, 0.f, 0.f, 0.f};
            a2 = __builtin_amdgcn_mfma_f32_16x16x32_bf16(wmf[0], hB[0], a2, 0, 0, 0);
            a2 = __builtin_amdgcn_mfma_f32_16x16x32_bf16(wmf[1], hB[1], a2, 0, 0, 0);
            if (q == 0) {
                const size_t tp = (size_t)c * S_LEN + (st - 1);
                *(float4*)(out + tp * 4) =
                    make_float4(a2[0] + bmv.x, a2[1] + bmv.y, a2[2] + bmv.z, a2[3] + bmv.w);
            }
        }
        // z add + tanh + pack into hB; mask-carry on packed words
        const bool upd = (mf != 0.0f);
        #pragma unroll
        for (int tn = 0; tn < 4; ++tn) {
            const unsigned short* zp = (const unsigned short*)&zc[tn * 2];
            float th[4];
            #pragma unroll
            for (int r = 0; r < 4; ++r)
                th[r] = fast_tanh(acc[tn][r] + bf2f(zp[r]));
            const unsigned w0 = pack2(th[0], th[1]);
            const unsigned w1 = pack2(th[2], th[3]);
            unsigned* hw = (unsigned*)&hB[tn >> 1];
            const int wi = (tn & 1) * 2;
            hw[wi + 0] = upd ? w0 : hw[wi + 0];
            hw[wi + 1] = upd ? w1 : hw[wi + 1];
        }
    };

    // warm: 16 steps (rolled)
    for (int st = -WARM; st < 0; ++st) body(st, false, true);
    // main: 8 steps, unrolled, means of prev step fused
    #pragma unroll
    for (int st = 0; st < S_LEN; ++st) body(st, st >= 1, st == 0);
    // tail flush: means for step S_LEN-1
    {
        f32x4 a2 = {0.f, 0.f, 0.f, 0.f};
        a2 = __builtin_amdgcn_mfma_f32_16x16x32_bf16(wmf[0], hB[0], a2, 0, 0, 0);
        a2 = __builtin_amdgcn_mfma_f32_16x16x32_bf16(wmf[1], hB[1], a2, 0, 0, 0);
        if (q == 0) {
            const size_t tp = (size_t)c * S_LEN + (S_LEN - 1);
            *(float4*)(out + tp * 4) =
                make_float4(a2[0] + bmv.x, a2[1] + bmv.y, a2[2] + bmv.z, a2[3] + bmv.w);
        }
    }
}

extern "C" void kernel_launch(void* const* d_in, const int* in_sizes, int n_in,
                              void* d_out, int out_size, void* d_ws, size_t ws_size,
                              hipStream_t stream) {
    const float* x     = (const float*)d_in[0];
    const float* W1    = (const float*)d_in[1];
    const float* b1    = (const float*)d_in[2];
    const float* W2    = (const float*)d_in[3];
    const float* b2    = (const float*)d_in[4];
    const float* Wx    = (const float*)d_in[5];
    const float* Wh    = (const float*)d_in[6];
    const float* b_rnn = (const float*)d_in[7];
    const float* Wm    = (const float*)d_in[8];
    const float* bm    = (const float*)d_in[9];
    float* out = (float*)d_out;

    // d_ws intentionally UNUSED: z/m live in wave-private LDS now, so this
    // kernel has no dependency on the workspace re-poison fill.
    (void)d_ws; (void)ws_size;

    fused_kernel<<<NWAVE / 4, 256, 0, stream>>>(
        x, W1, b1, W2, b2, Wx, b_rnn, Wh, Wm, bm, out);
}

// Round 6
// 131.992 us; speedup vs baseline: 1.0509x; 1.0509x over previous
//
#include <hip/hip_runtime.h>
#include <hip/hip_bf16.h>

// Problem constants (B=1)
constexpr int T_LEN  = 262144;
constexpr int H      = 64;
constexpr int S_LEN  = 8;                  // R13-validated
constexpr int WARM   = 16;                 // warm-up steps (contraction ~0.56/step -> 0.56^16 ~ 9e-5 << bf16-h floor)
constexpr int CHUNKS = T_LEN / S_LEN;      // 32768
constexpr int NWAVE  = CHUNKS / 16;        // 2048 RNN waves
constexpr int ZPAD_TAIL = 4;               // rows past T for harmless over-prefetch
constexpr int ROWS   = WARM + 128;         // 144 z rows per RNN wave
constexpr int ZDW_W  = ROWS * 32;          // 4608 z dwords per wave (stride 32 + XOR swizzle)
constexpr int MROWS  = 192;                // mask slots per wave (3 unguarded wave-loads)

typedef __attribute__((ext_vector_type(8))) short short8;  // 8 bf16 (4 VGPRs) MFMA A/B frag
typedef __attribute__((ext_vector_type(4))) float f32x4;   // MFMA C/D frag

// Saturation-safe fast tanh: 1 - 2/(exp(2x)+1). exp overflow -> rcp(inf)=0 -> 1. No NaN.
__device__ __forceinline__ float fast_tanh(float x) {
    float e = __expf(2.0f * x);
    return 1.0f - 2.0f * __builtin_amdgcn_rcpf(e + 1.0f);
}
// bf16 round-to-nearest-even pack / unpack (scalar fallback)
__device__ __forceinline__ unsigned short f2bf(float v) {
    unsigned u = __builtin_bit_cast(unsigned, v);
    return (unsigned short)((u + 0x7fffu + ((u >> 16) & 1u)) >> 16);
}
__device__ __forceinline__ float bf2f(unsigned short b) {
    return __builtin_bit_cast(float, (unsigned)b << 16);
}
// RNE pack of two floats -> packed bf16x2 (1-instruction v_cvt_pk_bf16_f32 when available)
__device__ __forceinline__ unsigned pack2(float a, float b) {
#if __has_builtin(__builtin_amdgcn_cvt_pk_bf16_f32)
    typedef __attribute__((ext_vector_type(2))) __bf16 bf16x2;
    bf16x2 r = __builtin_amdgcn_cvt_pk_bf16_f32(a, b);
    return __builtin_bit_cast(unsigned, r);
#else
    return (unsigned)f2bf(a) | ((unsigned)f2bf(b) << 16);
#endif
}

// ---------------------------------------------------------------------------
// K1: R14 pi-chained transposed encoder — UNCHANGED (validated bit-exact).
// ---------------------------------------------------------------------------
__global__ __launch_bounds__(256) void encoder_kernel(
    const float* __restrict__ x,
    const float* __restrict__ W1, const float* __restrict__ b1,
    const float* __restrict__ W2, const float* __restrict__ b2,
    const float* __restrict__ Wx, const float* __restrict__ b_rnn,
    unsigned short* __restrict__ z_s, float* __restrict__ m_s)
{
    __shared__ uint4 w1a[4 * 64];
    __shared__ uint4 w2a[8 * 64];
    __shared__ uint4 w3a[8 * 64];

    const int tid = threadIdx.x;
    const int w   = tid >> 6;
    const int l   = tid & 63;
    const int q   = l >> 4;
    const int n15 = l & 15;

    {
        const int smt = tid >> 6;
        const int sl  = tid & 63;
        const int sq  = sl >> 4;
        const int sn  = sl & 15;
        const int prow = 32 * (smt >> 1) + 8 * (sn >> 2) + 4 * (smt & 1) + (sn & 3);

        uint4 o1 = make_uint4(0, 0, 0, 0);
        if (sq < 2) {
            float v[8];
            #pragma unroll
            for (int j = 0; j < 8; ++j) v[j] = W1[j * 64 + prow];
            o1.x = pack2(v[0], v[1]); o1.y = pack2(v[2], v[3]);
            o1.z = pack2(v[4], v[5]); o1.w = pack2(v[6], v[7]);
        }
        w1a[smt * 64 + sl] = o1;

        #pragma unroll
        for (int kh = 0; kh < 2; ++kh) {
            float v2[8], v3[8];
            #pragma unroll
            for (int j = 0; j < 8; ++j) {
                const int k = kh * 32 + sq * 8 + j;
                v2[j] = W2[k * 64 + prow];
                v3[j] = Wx[k * 64 + prow];
            }
            uint4 o2, o3;
            o2.x = pack2(v2[0], v2[1]); o2.y = pack2(v2[2], v2[3]);
            o2.z = pack2(v2[4], v2[5]); o2.w = pack2(v2[6], v2[7]);
            o3.x = pack2(v3[0], v3[1]); o3.y = pack2(v3[2], v3[3]);
            o3.z = pack2(v3[4], v3[5]); o3.w = pack2(v3[6], v3[7]);
            w2a[(smt * 2 + kh) * 64 + sl] = o2;
            w3a[(smt * 2 + kh) * 64 + sl] = o3;
        }
    }
    __syncthreads();

    f32x4 b1v[4], b2v[4], brv[4];
    #pragma unroll
    for (int mt = 0; mt < 4; ++mt) {
        const int base = 32 * (mt >> 1) + 4 * (mt & 1) + 8 * q;
        b1v[mt] = *(const f32x4*)(b1 + base);
        b2v[mt] = *(const f32x4*)(b2 + base);
        brv[mt] = *(const f32x4*)(b_rnn + base);
    }

    float4 xa, xb;
    {
        const size_t t0 = (size_t)(blockIdx.x * 256 + w * 16 + n15) * 8;
        xa = *(const float4*)(x + t0);
        xb = *(const float4*)(x + t0 + 4);
    }

    #pragma unroll
    for (int it = 0; it < 4; ++it) {
        const int t = blockIdx.x * 256 + it * 64 + w * 16 + n15;

        float4 na = xa, nb = xb;
        if (it < 3) {
            const size_t tn0 = (size_t)(t + 64) * 8;
            na = *(const float4*)(x + tn0);
            nb = *(const float4*)(x + tn0 + 4);
        }

        short8 xB = (short8)0;
        {
            const float xv[8] = {xa.x, xa.y, xa.z, xa.w, xb.x, xb.y, xb.z, xb.w};
            if (q == 0) {
                bool nz = false;
                #pragma unroll
                for (int d = 0; d < 8; ++d) nz = nz || (xv[d] != 0.0f);
                m_s[t] = nz ? 1.0f : 0.0f;
                uint4 o;
                o.x = pack2(xv[0], xv[1]); o.y = pack2(xv[2], xv[3]);
                o.z = pack2(xv[4], xv[5]); o.w = pack2(xv[6], xv[7]);
                xB = __builtin_bit_cast(short8, o);
            } else if (q == 1) {
                float lo[8];
                #pragma unroll
                for (int d = 0; d < 8; ++d) lo[d] = xv[d] - bf2f(f2bf(xv[d]));
                uint4 o;
                o.x = pack2(lo[0], lo[1]); o.y = pack2(lo[2], lo[3]);
                o.z = pack2(lo[4], lo[5]); o.w = pack2(lo[6], lo[7]);
                xB = __builtin_bit_cast(short8, o);
            }
        }

        f32x4 acc[4];
        #pragma unroll
        for (int mt = 0; mt < 4; ++mt)
            acc[mt] = __builtin_amdgcn_mfma_f32_16x16x32_bf16(
                __builtin_bit_cast(short8, w1a[mt * 64 + l]), xB,
                (f32x4){0.f, 0.f, 0.f, 0.f}, 0, 0, 0);

        short8 hb0, hb1;
        {
            unsigned hw[8];
            #pragma unroll
            for (int mt = 0; mt < 4; ++mt) {
                float th[4];
                #pragma unroll
                for (int r = 0; r < 4; ++r)
                    th[r] = fast_tanh(acc[mt][r] + b1v[mt][r]);
                hw[mt * 2 + 0] = pack2(th[0], th[1]);
                hw[mt * 2 + 1] = pack2(th[2], th[3]);
            }
            hb0 = __builtin_bit_cast(short8, make_uint4(hw[0], hw[1], hw[2], hw[3]));
            hb1 = __builtin_bit_cast(short8, make_uint4(hw[4], hw[5], hw[6], hw[7]));
        }

        #pragma unroll
        for (int mt = 0; mt < 4; ++mt) {
            f32x4 d = {0.f, 0.f, 0.f, 0.f};
            d = __builtin_amdgcn_mfma_f32_16x16x32_bf16(
                    __builtin_bit_cast(short8, w2a[(mt * 2 + 0) * 64 + l]), hb0, d, 0, 0, 0);
            d = __builtin_amdgcn_mfma_f32_16x16x32_bf16(
                    __builtin_bit_cast(short8, w2a[(mt * 2 + 1) * 64 + l]), hb1, d, 0, 0, 0);
            acc[mt] = d;
        }
        {
            unsigned hw[8];
            #pragma unroll
            for (int mt = 0; mt < 4; ++mt) {
                float th[4];
                #pragma unroll
                for (int r = 0; r < 4; ++r)
                    th[r] = fast_tanh(acc[mt][r] + b2v[mt][r]);
                hw[mt * 2 + 0] = pack2(th[0], th[1]);
                hw[mt * 2 + 1] = pack2(th[2], th[3]);
            }
            hb0 = __builtin_bit_cast(short8, make_uint4(hw[0], hw[1], hw[2], hw[3]));
            hb1 = __builtin_bit_cast(short8, make_uint4(hw[4], hw[5], hw[6], hw[7]));
        }

        #pragma unroll
        for (int mt = 0; mt < 4; ++mt) {
            f32x4 d = {0.f, 0.f, 0.f, 0.f};
            d = __builtin_amdgcn_mfma_f32_16x16x32_bf16(
                    __builtin_bit_cast(short8, w3a[(mt * 2 + 0) * 64 + l]), hb0, d, 0, 0, 0);
            d = __builtin_amdgcn_mfma_f32_16x16x32_bf16(
                    __builtin_bit_cast(short8, w3a[(mt * 2 + 1) * 64 + l]), hb1, d, 0, 0, 0);
            acc[mt] = d;
        }

        {
            unsigned zw[8];
            #pragma unroll
            for (int mt = 0; mt < 4; ++mt) {
                float z0 = acc[mt][0] + brv[mt][0];
                float z1 = acc[mt][1] + brv[mt][1];
                float z2 = acc[mt][2] + brv[mt][2];
                float z3 = acc[mt][3] + brv[mt][3];
                zw[mt * 2 + 0] = pack2(z0, z1);
                zw[mt * 2 + 1] = pack2(z2, z3);
            }
            unsigned short* dst = z_s + (size_t)t * 64 + 8 * q;
            *(uint4*)(dst)      = make_uint4(zw[0], zw[1], zw[2], zw[3]);
            *(uint4*)(dst + 32) = make_uint4(zw[4], zw[5], zw[6], zw[7]);
        }

        xa = na; xb = nb;
    }
}

// ---------------------------------------------------------------------------
// K2 (R16): scan with LDS-STAGED z. R15's counters isolated the scan cost as
// scattered per-step z gathers from beyond-L2 (16 lines/instr, ~500-900cyc,
// 2 waves/SIMD). Fix: each wave bulk-stages its 144 CONTIGUOUS z rows
// (18,432B, 18 coalesced b128 loads — independent, MLP-covered) + masks into
// wave-private LDS, then runs the R13/R15 scan from LDS. Dword-group XOR
// swizzle v=((row>>3)^row)&7 makes BOTH the staging writes (keyed l>>3) and
// the scan reads (keyed n15) conflict-free (8 lanes/bank-quad = optimum).
// LDS 76.8KB/block -> 2 blocks/CU, 512 blocks all resident.
// Scan math identical to R13/R15 (staging is a bit-preserving copy);
// absmax tripwire = 0.001464844.
// ---------------------------------------------------------------------------
__global__ __launch_bounds__(256) void rnn_kernel(
    const unsigned short* __restrict__ z_pad, const float* __restrict__ m_pad,
    const float* __restrict__ Wh, const float* __restrict__ Wm,
    const float* __restrict__ bm, float* __restrict__ out)
{
    __shared__ unsigned zsh[4][ZDW_W];
    __shared__ float    msh[4][MROWS];

    const int tid = threadIdx.x;
    const int w   = tid >> 6;
    const int l   = tid & 63;
    const int q   = l >> 4;
    const int n15 = l & 15;
    const int rw  = blockIdx.x * 4 + w;   // global wave id
    const int c   = rw * 16 + n15;        // this lane's chunk

    unsigned* zw_ = zsh[w];

    // ---- stage: 18 coalesced b128 z loads + 3 mask loads, swizzled ds_write ----
    {
        const uint4* gz = (const uint4*)(z_pad + (size_t)rw * 128 * 64);
        #pragma unroll
        for (int k = 0; k < 18; ++k) {
            const uint4 v = gz[k * 64 + l];
            const int row = k * 8 + (l >> 3);
            const int grp = (l & 7) ^ ((k ^ (l >> 3)) & 7);
            *(uint4*)(zw_ + row * 32 + grp * 4) = v;
        }
        const float* gm = m_pad + (size_t)rw * 128;
        msh[w][l]       = gm[l];
        msh[w][64 + l]  = gm[64 + l];
        msh[w][128 + l] = gm[128 + l];   // rows >=144 unused; in-allocation over-read
    }
    __builtin_amdgcn_wave_barrier();
    asm volatile("s_waitcnt lgkmcnt(0)" ::: "memory");
    __builtin_amdgcn_sched_barrier(0);

    // ---- pi-permuted Wh^T A-fragments (R13 verbatim) ----
    short8 afrag[8];
    #pragma unroll
    for (int tn = 0; tn < 4; ++tn) {
        const int prow = 32 * (tn >> 1) + 8 * (n15 >> 2) + 4 * (tn & 1) + (n15 & 3);
        #pragma unroll
        for (int kh = 0; kh < 2; ++kh) {
            short8 s;
            #pragma unroll
            for (int j = 0; j < 8; ++j)
                s[j] = (short)f2bf(Wh[(kh * 32 + q * 8 + j) * 64 + prow]);
            afrag[tn * 2 + kh] = s;
        }
    }
    short8 wmf[2];
    #pragma unroll
    for (int kh = 0; kh < 2; ++kh) {
        short8 s;
        #pragma unroll
        for (int j = 0; j < 8; ++j)
            s[j] = (n15 < 4) ? (short)f2bf(Wm[(kh * 32 + q * 8 + j) * 4 + n15]) : (short)0;
        wmf[kh] = s;
    }
    const float4 bmv = *(const float4*)bm;

    short8 hB[2];
    hB[0] = (short8)0;
    hB[1] = (short8)0;
    const int tneg = -(c * S_LEN);        // st at which abs t == 0 (rw==0, n15<=2)

    auto body = [&](int st, bool means_prev, bool may_reset) {
        // z + mask from LDS (swizzled, conflict-free), issued first
        const int row = 8 * n15 + st + WARM;           // 0..143
        const int v   = ((row >> 3) ^ row) & 7;
        const unsigned* zr = zw_ + row * 32;
        const int g1 = (4 * q) ^ (v << 2);
        const uint4 z1 = *(const uint4*)(zr + g1);
        const uint4 z2 = *(const uint4*)(zr + (g1 ^ 16));
        const unsigned zc[8] = {z1.x, z1.y, z1.z, z1.w, z2.x, z2.y, z2.z, z2.w};
        const float mf = msh[w][row];

        if (may_reset && rw == 0) {       // uniform branch: 2047/2048 waves skip
            if (st == tneg) { hB[0] = (short8)0; hB[1] = (short8)0; }
        }
        // preact^T(pi) = pi-rows(Wh^T) @ h^T
        f32x4 acc[4];
        #pragma unroll
        for (int mt = 0; mt < 4; ++mt) {
            f32x4 d = {0.f, 0.f, 0.f, 0.f};
            d = __builtin_amdgcn_mfma_f32_16x16x32_bf16(afrag[mt * 2 + 0], hB[0], d, 0, 0, 0);
            d = __builtin_amdgcn_mfma_f32_16x16x32_bf16(afrag[mt * 2 + 1], hB[1], d, 0, 0, 0);
            acc[mt] = d;
        }
        // means of the PREVIOUS step's h
        if (means_prev) {
            f32x4 a2 = {0.f, 0.f, 0.f, 0.f};
            a2 = __builtin_amdgcn_mfma_f32_16x16x32_bf16(wmf[0], hB[0], a2, 0, 0, 0);
            a2 = __builtin_amdgcn_mfma_f32_16x16x32_bf16(wmf[1], hB[1], a2, 0, 0, 0);
            if (q == 0) {
                const size_t tp = (size_t)c * S_LEN + (st - 1);
                *(float4*)(out + tp * 4) =
                    make_float4(a2[0] + bmv.x, a2[1] + bmv.y, a2[2] + bmv.z, a2[3] + bmv.w);
            }
        }
        // z add + tanh + pack into hB; mask-carry on packed words
        const bool upd = (mf != 0.0f);
        #pragma unroll
        for (int tn = 0; tn < 4; ++tn) {
            const unsigned short* zp = (const unsigned short*)&zc[tn * 2];
            float th[4];
            #pragma unroll
            for (int r = 0; r < 4; ++r)
                th[r] = fast_tanh(acc[tn][r] + bf2f(zp[r]));
            const unsigned w0 = pack2(th[0], th[1]);
            const unsigned w1 = pack2(th[2], th[3]);
            unsigned* hw = (unsigned*)&hB[tn >> 1];
            const int wi = (tn & 1) * 2;
            hw[wi + 0] = upd ? w0 : hw[wi + 0];
            hw[wi + 1] = upd ? w1 : hw[wi + 1];
        }
    };

    // warm: 16 steps (rolled)
    for (int st = -WARM; st < 0; ++st) body(st, false, true);
    // main: 8 steps, unrolled
    #pragma unroll
    for (int st = 0; st < S_LEN; ++st) body(st, st >= 1, st == 0);
    // tail flush: means for step S_LEN-1
    {
        f32x4 a2 = {0.f, 0.f, 0.f, 0.f};
        a2 = __builtin_amdgcn_mfma_f32_16x16x32_bf16(wmf[0], hB[0], a2, 0, 0, 0);
        a2 = __builtin_amdgcn_mfma_f32_16x16x32_bf16(wmf[1], hB[1], a2, 0, 0, 0);
        if (q == 0) {
            const size_t tp = (size_t)c * S_LEN + (S_LEN - 1);
            *(float4*)(out + tp * 4) =
                make_float4(a2[0] + bmv.x, a2[1] + bmv.y, a2[2] + bmv.z, a2[3] + bmv.w);
        }
    }
}

extern "C" void kernel_launch(void* const* d_in, const int* in_sizes, int n_in,
                              void* d_out, int out_size, void* d_ws, size_t ws_size,
                              hipStream_t stream) {
    const float* x     = (const float*)d_in[0];
    const float* W1    = (const float*)d_in[1];
    const float* b1    = (const float*)d_in[2];
    const float* W2    = (const float*)d_in[3];
    const float* b2    = (const float*)d_in[4];
    const float* Wx    = (const float*)d_in[5];
    const float* Wh    = (const float*)d_in[6];
    const float* b_rnn = (const float*)d_in[7];
    const float* Wm    = (const float*)d_in[8];
    const float* bm    = (const float*)d_in[9];
    float* out = (float*)d_out;

    // Workspace layout (front-padded by WARM rows; pad contents = poison, OK):
    //   z_pad: (WARM + T + ZPAD_TAIL) rows x 64 bf16
    //   m_pad: (WARM + T + ZPAD_TAIL) floats
    unsigned short* z_pad = (unsigned short*)d_ws;
    const size_t z_rows   = (size_t)(WARM + T_LEN + ZPAD_TAIL);
    float*          m_pad = (float*)((char*)d_ws + z_rows * H * 2);

    unsigned short* z_s = z_pad + (size_t)WARM * H;   // abs t=0 row
    float*          m_s = m_pad + WARM;

    encoder_kernel<<<T_LEN / 256, 256, 0, stream>>>(x, W1, b1, W2, b2, Wx, b_rnn, z_s, m_s);
    rnn_kernel<<<NWAVE / 4, 256, 0, stream>>>(z_pad, m_pad, Wh, Wm, bm, out);
}

// Round 7
// 129.165 us; speedup vs baseline: 1.0739x; 1.0219x over previous
//
#include <hip/hip_runtime.h>
#include <hip/hip_bf16.h>

// Problem constants (B=1)
constexpr int T_LEN  = 262144;
constexpr int H      = 64;
constexpr int S_LEN  = 8;                  // R13-validated
constexpr int WARM   = 16;                 // warm-up steps (contraction ~0.56/step -> 0.56^16 ~ 9e-5 << bf16-h floor)
constexpr int CHUNKS = T_LEN / S_LEN;      // 32768
constexpr int NWAVE  = CHUNKS / 16;        // 2048 RNN waves
constexpr int ZPAD_TAIL = 4;               // rows past T for harmless over-prefetch

typedef __attribute__((ext_vector_type(8))) short short8;  // 8 bf16 (4 VGPRs) MFMA A/B frag
typedef __attribute__((ext_vector_type(4))) float f32x4;   // MFMA C/D frag

// Saturation-safe fast tanh: 1 - 2/(exp(2x)+1). exp overflow -> rcp(inf)=0 -> 1. No NaN.
__device__ __forceinline__ float fast_tanh(float x) {
    float e = __expf(2.0f * x);
    return 1.0f - 2.0f * __builtin_amdgcn_rcpf(e + 1.0f);
}
// bf16 round-to-nearest-even pack / unpack (scalar fallback)
__device__ __forceinline__ unsigned short f2bf(float v) {
    unsigned u = __builtin_bit_cast(unsigned, v);
    return (unsigned short)((u + 0x7fffu + ((u >> 16) & 1u)) >> 16);
}
__device__ __forceinline__ float bf2f(unsigned short b) {
    return __builtin_bit_cast(float, (unsigned)b << 16);
}
// RNE pack of two floats -> packed bf16x2 (1-instruction v_cvt_pk_bf16_f32 when available)
__device__ __forceinline__ unsigned pack2(float a, float b) {
#if __has_builtin(__builtin_amdgcn_cvt_pk_bf16_f32)
    typedef __attribute__((ext_vector_type(2))) __bf16 bf16x2;
    bf16x2 r = __builtin_amdgcn_cvt_pk_bf16_f32(a, b);
    return __builtin_bit_cast(unsigned, r);
#else
    return (unsigned)f2bf(a) | ((unsigned)f2bf(b) << 16);
#endif
}

// ---------------------------------------------------------------------------
// K1 (R14, best-measured): pi-chained TRANSPOSED encoder — zero scratch LDS,
// zero in-loop barriers. Computes h^T = Wpi^T @ x^T per layer with weight
// OUTPUT rows pre-permuted by pi(16*mt+4*q+r) = 32*(mt>>1)+8*q+4*(mt&1)+r,
// so each layer's packed MFMA D output IS the next layer's B-fragment.
// Bit-exact (absmax tripwire = 0.001464844).
// ---------------------------------------------------------------------------
__global__ __launch_bounds__(256) void encoder_kernel(
    const float* __restrict__ x,
    const float* __restrict__ W1, const float* __restrict__ b1,
    const float* __restrict__ W2, const float* __restrict__ b2,
    const float* __restrict__ Wx, const float* __restrict__ b_rnn,
    unsigned short* __restrict__ z_s, float* __restrict__ m_s)
{
    __shared__ uint4 w1a[4 * 64];   // pi-rows W1^T A-frags (K=32: q<2 = hi/lo weights, q>=2 zero)
    __shared__ uint4 w2a[8 * 64];   // pi-rows W2^T A-frags (K=64: 2 k-halves)
    __shared__ uint4 w3a[8 * 64];   // pi-rows Wx^T A-frags

    const int tid = threadIdx.x;
    const int w   = tid >> 6;
    const int l   = tid & 63;
    const int q   = l >> 4;
    const int n15 = l & 15;

    // ---- stage pi-permuted W^T A-fragments (RNE bf16), one entry per (tile, lane) ----
    {
        const int smt = tid >> 6;        // tile 0..3
        const int sl  = tid & 63;        // lane slot
        const int sq  = sl >> 4;
        const int sn  = sl & 15;
        const int prow = 32 * (smt >> 1) + 8 * (sn >> 2) + 4 * (smt & 1) + (sn & 3);

        // W1: A[16*smt+sn][k=sq*8+j] ; k in [0,16) = Dekker hi/lo sharing W1 rows, rest 0
        uint4 o1 = make_uint4(0, 0, 0, 0);
        if (sq < 2) {
            float v[8];
            #pragma unroll
            for (int j = 0; j < 8; ++j) v[j] = W1[j * 64 + prow];
            o1.x = pack2(v[0], v[1]); o1.y = pack2(v[2], v[3]);
            o1.z = pack2(v[4], v[5]); o1.w = pack2(v[6], v[7]);
        }
        w1a[smt * 64 + sl] = o1;

        #pragma unroll
        for (int kh = 0; kh < 2; ++kh) {
            float v2[8], v3[8];
            #pragma unroll
            for (int j = 0; j < 8; ++j) {
                const int k = kh * 32 + sq * 8 + j;
                v2[j] = W2[k * 64 + prow];
                v3[j] = Wx[k * 64 + prow];
            }
            uint4 o2, o3;
            o2.x = pack2(v2[0], v2[1]); o2.y = pack2(v2[2], v2[3]);
            o2.z = pack2(v2[4], v2[5]); o2.w = pack2(v2[6], v2[7]);
            o3.x = pack2(v3[0], v3[1]); o3.y = pack2(v3[2], v3[3]);
            o3.z = pack2(v3[4], v3[5]); o3.w = pack2(v3[6], v3[7]);
            w2a[(smt * 2 + kh) * 64 + sl] = o2;
            w3a[(smt * 2 + kh) * 64 + sl] = o3;
        }
    }
    __syncthreads();

    // biases per lane, float4 per tile: feature base = 32*(mt>>1) + 4*(mt&1) + 8q
    f32x4 b1v[4], b2v[4], brv[4];
    #pragma unroll
    for (int mt = 0; mt < 4; ++mt) {
        const int base = 32 * (mt >> 1) + 4 * (mt & 1) + 8 * q;
        b1v[mt] = *(const f32x4*)(b1 + base);
        b2v[mt] = *(const f32x4*)(b2 + base);
        brv[mt] = *(const f32x4*)(b_rnn + base);
    }

    // prefetch iter 0's x row (t = n15 within this wave's 16-row group)
    float4 xa, xb;
    {
        const size_t t0 = (size_t)(blockIdx.x * 256 + w * 16 + n15) * 8;
        xa = *(const float4*)(x + t0);
        xb = *(const float4*)(x + t0 + 4);
    }

    #pragma unroll
    for (int it = 0; it < 4; ++it) {
        const int t = blockIdx.x * 256 + it * 64 + w * 16 + n15;

        // issue iter+1's x load NOW
        float4 na = xa, nb = xb;
        if (it < 3) {
            const size_t tn0 = (size_t)(t + 64) * 8;
            na = *(const float4*)(x + tn0);
            nb = *(const float4*)(x + tn0 + 4);
        }

        // ---- x^T B-frag, Dekker-split: q=0 -> hi (k 0..7), q=1 -> lo (k 8..15) ----
        short8 xB = (short8)0;
        {
            const float xv[8] = {xa.x, xa.y, xa.z, xa.w, xb.x, xb.y, xb.z, xb.w};
            if (q == 0) {
                bool nz = false;
                #pragma unroll
                for (int d = 0; d < 8; ++d) nz = nz || (xv[d] != 0.0f);
                m_s[t] = nz ? 1.0f : 0.0f;
                uint4 o;
                o.x = pack2(xv[0], xv[1]); o.y = pack2(xv[2], xv[3]);
                o.z = pack2(xv[4], xv[5]); o.w = pack2(xv[6], xv[7]);
                xB = __builtin_bit_cast(short8, o);
            } else if (q == 1) {
                float lo[8];
                #pragma unroll
                for (int d = 0; d < 8; ++d) lo[d] = xv[d] - bf2f(f2bf(xv[d]));
                uint4 o;
                o.x = pack2(lo[0], lo[1]); o.y = pack2(lo[2], lo[3]);
                o.z = pack2(lo[4], lo[5]); o.w = pack2(lo[6], lo[7]);
                xB = __builtin_bit_cast(short8, o);
            }
        }

        // ---- L1: h1^T(pi) = W1pi^T @ x^T ----
        f32x4 acc[4];
        #pragma unroll
        for (int mt = 0; mt < 4; ++mt)
            acc[mt] = __builtin_amdgcn_mfma_f32_16x16x32_bf16(
                __builtin_bit_cast(short8, w1a[mt * 64 + l]), xB,
                (f32x4){0.f, 0.f, 0.f, 0.f}, 0, 0, 0);

        // tanh + b1 -> packed B-frags (D-to-B identity: word (mt&1)*2+{0,1} of half mt>>1)
        short8 hb0, hb1;
        {
            unsigned hw[8];
            #pragma unroll
            for (int mt = 0; mt < 4; ++mt) {
                float th[4];
                #pragma unroll
                for (int r = 0; r < 4; ++r)
                    th[r] = fast_tanh(acc[mt][r] + b1v[mt][r]);
                hw[mt * 2 + 0] = pack2(th[0], th[1]);
                hw[mt * 2 + 1] = pack2(th[2], th[3]);
            }
            hb0 = __builtin_bit_cast(short8, make_uint4(hw[0], hw[1], hw[2], hw[3]));
            hb1 = __builtin_bit_cast(short8, make_uint4(hw[4], hw[5], hw[6], hw[7]));
        }

        // ---- L2: h2^T(pi) = W2pi^T @ h1^T ----
        #pragma unroll
        for (int mt = 0; mt < 4; ++mt) {
            f32x4 d = {0.f, 0.f, 0.f, 0.f};
            d = __builtin_amdgcn_mfma_f32_16x16x32_bf16(
                    __builtin_bit_cast(short8, w2a[(mt * 2 + 0) * 64 + l]), hb0, d, 0, 0, 0);
            d = __builtin_amdgcn_mfma_f32_16x16x32_bf16(
                    __builtin_bit_cast(short8, w2a[(mt * 2 + 1) * 64 + l]), hb1, d, 0, 0, 0);
            acc[mt] = d;
        }
        {
            unsigned hw[8];
            #pragma unroll
            for (int mt = 0; mt < 4; ++mt) {
                float th[4];
                #pragma unroll
                for (int r = 0; r < 4; ++r)
                    th[r] = fast_tanh(acc[mt][r] + b2v[mt][r]);
                hw[mt * 2 + 0] = pack2(th[0], th[1]);
                hw[mt * 2 + 1] = pack2(th[2], th[3]);
            }
            hb0 = __builtin_bit_cast(short8, make_uint4(hw[0], hw[1], hw[2], hw[3]));
            hb1 = __builtin_bit_cast(short8, make_uint4(hw[4], hw[5], hw[6], hw[7]));
        }

        // ---- L3: z^T(pi) = Wxpi^T @ h2^T + b_rnn ----
        #pragma unroll
        for (int mt = 0; mt < 4; ++mt) {
            f32x4 d = {0.f, 0.f, 0.f, 0.f};
            d = __builtin_amdgcn_mfma_f32_16x16x32_bf16(
                    __builtin_bit_cast(short8, w3a[(mt * 2 + 0) * 64 + l]), hb0, d, 0, 0, 0);
            d = __builtin_amdgcn_mfma_f32_16x16x32_bf16(
                    __builtin_bit_cast(short8, w3a[(mt * 2 + 1) * 64 + l]), hb1, d, 0, 0, 0);
            acc[mt] = d;
        }

        // ---- z -> RNE bf16, natural [t][64]: lane holds feats [8q,8q+8) and [32+8q,+8) ----
        {
            unsigned zw[8];
            #pragma unroll
            for (int mt = 0; mt < 4; ++mt) {
                float z0 = acc[mt][0] + brv[mt][0];
                float z1 = acc[mt][1] + brv[mt][1];
                float z2 = acc[mt][2] + brv[mt][2];
                float z3 = acc[mt][3] + brv[mt][3];
                zw[mt * 2 + 0] = pack2(z0, z1);
                zw[mt * 2 + 1] = pack2(z2, z3);
            }
            unsigned short* dst = z_s + (size_t)t * 64 + 8 * q;
            *(uint4*)(dst)      = make_uint4(zw[0], zw[1], zw[2], zw[3]);
            *(uint4*)(dst + 32) = make_uint4(zw[4], zw[5], zw[6], zw[7]);
        }

        xa = na; xb = nb;
    }
}

// ---------------------------------------------------------------------------
// K2: R13 rnn_kernel, UNCHANGED (validated bit-exact; absmax tripwire).
// ---------------------------------------------------------------------------
__global__ __launch_bounds__(256) void rnn_kernel(
    const unsigned short* __restrict__ z_pad, const float* __restrict__ m_pad,
    const float* __restrict__ Wh, const float* __restrict__ Wm,
    const float* __restrict__ bm, float* __restrict__ out)
{
    const int tid = threadIdx.x;
    const int w   = tid >> 6;
    const int l   = tid & 63;
    const int q   = l >> 4;
    const int n15 = l & 15;
    const int rw  = blockIdx.x * 4 + w;   // global wave id
    const int c   = rw * 16 + n15;        // this lane's chunk (D/B col n = n15)

    // pi-permuted Wh^T A-fragments
    short8 afrag[8];
    #pragma unroll
    for (int tn = 0; tn < 4; ++tn) {
        const int prow = 32 * (tn >> 1) + 8 * (n15 >> 2) + 4 * (tn & 1) + (n15 & 3);
        #pragma unroll
        for (int kh = 0; kh < 2; ++kh) {
            short8 s;
            #pragma unroll
            for (int j = 0; j < 8; ++j)
                s[j] = (short)f2bf(Wh[(kh * 32 + q * 8 + j) * 64 + prow]);
            afrag[tn * 2 + kh] = s;
        }
    }
    // Wm^T A-fragment: rows 0..3 valid (mean index), rest zero
    short8 wmf[2];
    #pragma unroll
    for (int kh = 0; kh < 2; ++kh) {
        short8 s;
        #pragma unroll
        for (int j = 0; j < 8; ++j)
            s[j] = (n15 < 4) ? (short)f2bf(Wm[(kh * 32 + q * 8 + j) * 4 + n15]) : (short)0;
        wmf[kh] = s;
    }
    const float4 bmv = *(const float4*)bm;   // bm[0..3], used by q==0 lanes

    // h state: ONLY the bf16 B-frags. hB[half] element j = h[chunk n15][feat half*32+8q+j].
    short8 hB[2];
    hB[0] = (short8)0;
    hB[1] = (short8)0;

    // per-lane linear pointers into the PADDED arrays (padded row 0 = abs t -WARM)
    const unsigned short* zrow = z_pad + (size_t)c * S_LEN * 64;
    const float*          mrow = m_pad + (size_t)c * S_LEN;
    const int tneg = -(c * S_LEN);        // st at which abs t == 0

    // z load offset for acc-tile tn under pi: feat base = 32*(tn>>1) + 8q + 4*(tn&1)
    const int zo0 = 8 * q;            // tn=0
    const int zo1 = 8 * q + 4;        // tn=1
    const int zo2 = 8 * q + 32;       // tn=2
    const int zo3 = 8 * q + 36;       // tn=3

    // preload steps st=-WARM (parity 0) and st=-WARM+1 (parity 1)
    uint2 zb0[4], zb1[4];
    float mb0, mb1;
    {
        zb0[0] = *(const uint2*)(zrow + zo0);
        zb0[1] = *(const uint2*)(zrow + zo1);
        zb0[2] = *(const uint2*)(zrow + zo2);
        zb0[3] = *(const uint2*)(zrow + zo3);
        zb1[0] = *(const uint2*)(zrow + 64 + zo0);
        zb1[1] = *(const uint2*)(zrow + 64 + zo1);
        zb1[2] = *(const uint2*)(zrow + 64 + zo2);
        zb1[3] = *(const uint2*)(zrow + 64 + zo3);
    }
    mb0 = mrow[0];
    mb1 = mrow[1];
    zrow += 128; mrow += 2;               // -> reload row for st=-WARM (i.e. st+2)

    // body: consume (zbuf,mref) for step st, then reload them from (zrl,mrl) = st+2
    auto body = [&](uint2* zbuf, float& mref,
                    const unsigned short* zrl, const float* mrl,
                    int stv, bool means_prev, bool may_reset) {
        if (may_reset && rw == 0) {       // uniform branch: 2047/2048 waves skip
            if (stv == tneg) {            // per-lane (tneg depends on n15)
                hB[0] = (short8)0; hB[1] = (short8)0;
            }
        }
        // preact^T(pi) = pi-rows(Wh^T) @ h^T
        f32x4 acc[4];
        #pragma unroll
        for (int mt = 0; mt < 4; ++mt) {
            f32x4 d = {0.f, 0.f, 0.f, 0.f};
            d = __builtin_amdgcn_mfma_f32_16x16x32_bf16(afrag[mt * 2 + 0], hB[0], d, 0, 0, 0);
            d = __builtin_amdgcn_mfma_f32_16x16x32_bf16(afrag[mt * 2 + 1], hB[1], d, 0, 0, 0);
            acc[mt] = d;
        }
        // means of the PREVIOUS step's h (hB not yet updated)
        if (means_prev) {
            f32x4 a2 = {0.f, 0.f, 0.f, 0.f};
            a2 = __builtin_amdgcn_mfma_f32_16x16x32_bf16(wmf[0], hB[0], a2, 0, 0, 0);
            a2 = __builtin_amdgcn_mfma_f32_16x16x32_bf16(wmf[1], hB[1], a2, 0, 0, 0);
            if (q == 0) {
                const size_t tp = (size_t)c * S_LEN + (stv - 1);
                *(float4*)(out + tp * 4) =
                    make_float4(a2[0] + bmv.x, a2[1] + bmv.y, a2[2] + bmv.z, a2[3] + bmv.w);
            }
        }
        // z add + tanh + pack straight into hB; mask-carry on packed words.
        const bool upd = (mref != 0.0f);
        #pragma unroll
        for (int tn = 0; tn < 4; ++tn) {
            const unsigned short* zp = (const unsigned short*)&zbuf[tn];
            float th[4];
            #pragma unroll
            for (int r = 0; r < 4; ++r)
                th[r] = fast_tanh(acc[tn][r] + bf2f(zp[r]));
            const unsigned w0 = pack2(th[0], th[1]);
            const unsigned w1 = pack2(th[2], th[3]);
            unsigned* hw = (unsigned*)&hB[tn >> 1];
            const int wi = (tn & 1) * 2;
            hw[wi + 0] = upd ? w0 : hw[wi + 0];
            hw[wi + 1] = upd ? w1 : hw[wi + 1];
        }
        // reload this parity's buffers for step st+2 (wait lands a full body later)
        zbuf[0] = *(const uint2*)(zrl + zo0);
        zbuf[1] = *(const uint2*)(zrl + zo1);
        zbuf[2] = *(const uint2*)(zrl + zo2);
        zbuf[3] = *(const uint2*)(zrl + zo3);
        mref = mrl[0];
    };

    // ---- warm loop: 16 steps, parity-pair per iteration ----
    for (int i = 0; i < WARM / 2; ++i) {
        const int st = -WARM + 2 * i;
        body(zb0, mb0, zrow,      mrow,     st,     false, true);
        body(zb1, mb1, zrow + 64, mrow + 1, st + 1, false, true);
        zrow += 128; mrow += 2;
    }

    // ---- main loop: 8 steps, fully unrolled ----
    #pragma unroll
    for (int st = 0; st < S_LEN; ++st) {
        if ((st & 1) == 0)
            body(zb0, mb0, zrow + st * 64, mrow + st, st, st >= 1, st == 0);
        else
            body(zb1, mb1, zrow + st * 64, mrow + st, st, true, false);
    }

    // tail flush: means for step S_LEN-1
    {
        f32x4 a2 = {0.f, 0.f, 0.f, 0.f};
        a2 = __builtin_amdgcn_mfma_f32_16x16x32_bf16(wmf[0], hB[0], a2, 0, 0, 0);
        a2 = __builtin_amdgcn_mfma_f32_16x16x32_bf16(wmf[1], hB[1], a2, 0, 0, 0);
        if (q == 0) {
            const size_t tp = (size_t)c * S_LEN + (S_LEN - 1);
            *(float4*)(out + tp * 4) =
                make_float4(a2[0] + bmv.x, a2[1] + bmv.y, a2[2] + bmv.z, a2[3] + bmv.w);
        }
    }
}

extern "C" void kernel_launch(void* const* d_in, const int* in_sizes, int n_in,
                              void* d_out, int out_size, void* d_ws, size_t ws_size,
                              hipStream_t stream) {
    const float* x     = (const float*)d_in[0];
    const float* W1    = (const float*)d_in[1];
    const float* b1    = (const float*)d_in[2];
    const float* W2    = (const float*)d_in[3];
    const float* b2    = (const float*)d_in[4];
    const float* Wx    = (const float*)d_in[5];
    const float* Wh    = (const float*)d_in[6];
    const float* b_rnn = (const float*)d_in[7];
    const float* Wm    = (const float*)d_in[8];
    const float* bm    = (const float*)d_in[9];
    float* out = (float*)d_out;

    // Workspace layout (front-padded by WARM rows; pad contents = poison, OK):
    //   z_pad: (WARM + T + ZPAD_TAIL) rows x 64 bf16
    //   m_pad: (WARM + T + ZPAD_TAIL) floats
    unsigned short* z_pad = (unsigned short*)d_ws;
    const size_t z_rows   = (size_t)(WARM + T_LEN + ZPAD_TAIL);
    float*          m_pad = (float*)((char*)d_ws + z_rows * H * 2);

    unsigned short* z_s = z_pad + (size_t)WARM * H;   // abs t=0 row
    float*          m_s = m_pad + WARM;

    encoder_kernel<<<T_LEN / 256, 256, 0, stream>>>(x, W1, b1, W2, b2, Wx, b_rnn, z_s, m_s);
    rnn_kernel<<<NWAVE / 4, 256, 0, stream>>>(z_pad, m_pad, Wh, Wm, bm, out);
}